// Round 5
// baseline (266.125 us; speedup 1.0000x reference)
//
#include <hip/hip_runtime.h>
#include <hip/hip_cooperative_groups.h>
#include <cstddef>

namespace cg = cooperative_groups;

// VectorizedPatchfier: capacity-limited stable counting sort into per-patch buffers.
// B=8, S=1<<20, C=4, grid 4x4 patches of 128x128 over a 512x512 canvas.
// Single cooperative kernel: hist prefix tiles (cached in LDS) -> grid.sync ->
// parallel scan -> grid.sync -> scatter from LDS. Suffix of each batch is only
// touched via the (never-triggered for uniform input, 21-sigma) fallback phase D.

#define GRID_W 4
#define GRID_H 4
#define NPATCH 16
#define PATCH_SHIFT 7   // 128
#define S_LEN (1 << 20)
#define TILE 2048
#define CHUNK (TILE / 4)    // events per wave
#define ITERS (CHUNK / 64)  // inner iterations per wave
#define T1PB_MAX 128

__device__ __forceinline__ int patch_of(float fx, float fy) {
    int px = ((int)fx) >> PATCH_SHIFT;
    int py = ((int)fy) >> PATCH_SHIFT;
    px = px < 0 ? 0 : (px > GRID_W - 1 ? GRID_W - 1 : px);
    py = py < 0 ? 0 : (py > GRID_H - 1 ? GRID_H - 1 : py);
    return (py << 2) | px;
}

// Per-wave: mask of lanes whose 4-bit patch id matches this lane's.
__device__ __forceinline__ unsigned long long same_mask4(int p) {
    unsigned long long same = ~0ull;
#pragma unroll
    for (int b = 0; b < 4; ++b) {
        unsigned long long bal = __ballot((p >> b) & 1);
        same &= ((p >> b) & 1) ? bal : ~bal;
    }
    return same;
}

__global__ __launch_bounds__(256, 3) void k_fused(
    const float4* __restrict__ ev, unsigned* __restrict__ counts,
    unsigned* __restrict__ satflag, unsigned* __restrict__ tot1,
    const int* __restrict__ p_cap, float* __restrict__ out,
    int tpb, int T1pb, int B) {
    cg::grid_group grid = cg::this_grid();
    const int blk = blockIdx.x;
    const int b = blk / T1pb, tloc = blk - b * T1pb;
    const int t = b * tpb + tloc;
    const int tid = threadIdx.x, lane = tid & 63, w = tid >> 6;
    const unsigned cap = (unsigned)p_cap[0];
    const unsigned long long lt = (1ull << lane) - 1ull;

    __shared__ float4 s_ev[TILE];                 // 32 KB: this block's tile
    __shared__ unsigned sc[T1PB_MAX * NPATCH];    // 8 KB: scan scratch
    __shared__ unsigned part[NPATCH * 17];
    __shared__ unsigned wh[4][NPATCH];
    __shared__ unsigned cnt[4][NPATCH];
    __shared__ unsigned base_off[NPATCH];
    __shared__ unsigned s_tot[NPATCH];
    __shared__ int s_flag;

    float* __restrict__ out_mask = out + (size_t)B * NPATCH * cap * 4;

    // ---- Phase A: load own tile to LDS + per-wave histogram ----
    if (tid < 64) wh[tid >> 4][tid & 15] = 0;
    __syncthreads();
    {
        const size_t gbase = (size_t)t * TILE;
        for (int it = 0; it < ITERS; ++it) {
            int idx = w * CHUNK + it * 64 + lane;
            float4 e = ev[gbase + idx];
            s_ev[idx] = e;
            int p = patch_of(e.x, e.y);
            unsigned long long same = same_mask4(p);
            if ((same & lt) == 0ull) wh[w][p] += (unsigned)__popcll(same);
        }
    }
    __syncthreads();
    if (tid < NPATCH)
        counts[(size_t)t * NPATCH + tid] =
            wh[0][tid] + wh[1][tid] + wh[2][tid] + wh[3][tid];

    __threadfence();
    grid.sync();

    // ---- Phase B: per-batch parallel scan of prefix counts (blocks 0..B-1) ----
    if (blk < B) {
        const size_t cb = (size_t)blk * tpb * NPATCH;
        for (int i = tid; i < T1pb * NPATCH; i += 256) sc[i] = counts[cb + i];
        __syncthreads();
        const int p = tid & 15, j = tid >> 4;  // 16 segments x 16 patches
        const int seg = (T1pb + 15) >> 4;
        unsigned psum = 0;
        for (int k = 0; k < seg; ++k) {
            int tt = j * seg + k;
            if (tt < T1pb) psum += sc[tt * NPATCH + p];
        }
        part[p * 17 + j] = psum;
        __syncthreads();
        for (int d = 1; d < 16; d <<= 1) {
            unsigned x = (j >= d) ? part[p * 17 + j - d] : 0u;
            __syncthreads();
            part[p * 17 + j] += x;
            __syncthreads();
        }
        unsigned excl = part[p * 17 + j] - psum;
        unsigned total = part[p * 17 + 15];
        unsigned run = excl;
        for (int k = 0; k < seg; ++k) {
            int tt = j * seg + k;
            if (tt < T1pb) {
                unsigned v = sc[tt * NPATCH + p];
                sc[tt * NPATCH + p] = run;
                run += v;
            }
        }
        if (j == 0) s_tot[p] = total;
        __syncthreads();
        for (int i = tid; i < T1pb * NPATCH; i += 256) counts[cb + i] = sc[i];
        if (tid < NPATCH) tot1[blk * NPATCH + tid] = s_tot[tid];
        if (tid == 0) {
            int ok = 1;
            for (int p2 = 0; p2 < NPATCH; ++p2) ok &= (s_tot[p2] >= cap) ? 1 : 0;
            satflag[blk] = (unsigned)ok;
        }
    }

    __threadfence();
    grid.sync();

    // grid-uniform saturation decision
    if (tid == 0) s_flag = 1;
    __syncthreads();
    if (tid < B && satflag[tid] == 0u) s_flag = 0;  // benign race
    __syncthreads();
    const bool allsat = (s_flag != 0);

    // ---- Phase C: scatter own tile from LDS ----
    if (tid < NPATCH) base_off[tid] = counts[(size_t)t * NPATCH + tid];
    if (tid == 0) s_flag = 0;
    __syncthreads();
    if (tid < NPATCH && base_off[tid] < cap) s_flag = 1;  // benign race
    __syncthreads();
    if (s_flag) {
        if (tid < 64) {
            int ww = tid >> 4, p = tid & 15;
            unsigned s = base_off[p];
            for (int w2 = 0; w2 < ww; ++w2) s += wh[w2][p];
            cnt[ww][p] = s;
        }
        __syncthreads();
        for (int it = 0; it < ITERS; ++it) {
            float4 e = s_ev[w * CHUNK + it * 64 + lane];
            int px = ((int)e.x) >> PATCH_SHIFT;
            px = px < 0 ? 0 : (px > GRID_W - 1 ? GRID_W - 1 : px);
            int py = ((int)e.y) >> PATCH_SHIFT;
            py = py < 0 ? 0 : (py > GRID_H - 1 ? GRID_H - 1 : py);
            int p = (py << 2) | px;
            unsigned long long same = same_mask4(p);
            unsigned before = (unsigned)__popcll(same & lt);
            unsigned cb2 = cnt[w][p];
            unsigned rank = cb2 + before;
            if (rank < cap) {
                size_t o = ((size_t)b * NPATCH + p) * cap + rank;
                float4 v;
                v.x = e.x - (float)(px << PATCH_SHIFT);
                v.y = e.y - (float)(py << PATCH_SHIFT);
                v.z = e.z;
                v.w = e.w;
                ((float4*)out)[o] = v;
                out_mask[o] = 1.0f;
            }
            if (before == 0) cnt[w][p] = cb2 + (unsigned)__popcll(same);
        }
    }

    if (allsat) return;  // fast path: suffix provably all-beyond-capacity

    // ==== Phase D (fallback, grid-uniform): finish suffix correctly ====
    const int nsuf = tpb - T1pb;

    // D0: histogram suffix tiles of unsaturated batches (grid-stride)
    for (int s = blk; s < B * nsuf; s += gridDim.x) {
        int b2 = s / nsuf;
        if (satflag[b2]) continue;  // block-uniform
        int t2 = b2 * tpb + T1pb + (s - b2 * nsuf);
        __syncthreads();
        if (tid < 64) wh[tid >> 4][tid & 15] = 0;
        __syncthreads();
        const size_t gbase = (size_t)t2 * TILE;
        for (int it = 0; it < ITERS; ++it) {
            float4 e = ev[gbase + w * CHUNK + it * 64 + lane];
            int p = patch_of(e.x, e.y);
            unsigned long long same = same_mask4(p);
            if ((same & lt) == 0ull) wh[w][p] += (unsigned)__popcll(same);
        }
        __syncthreads();
        if (tid < NPATCH)
            counts[(size_t)t2 * NPATCH + tid] =
                wh[0][tid] + wh[1][tid] + wh[2][tid] + wh[3][tid];
    }
    __threadfence();
    grid.sync();

    // D1: scan suffix (chunked through LDS) + zero unfilled tails
    if (blk < B && !satflag[blk]) {
        if (tid < NPATCH) s_tot[tid] = tot1[blk * NPATCH + tid];
        __syncthreads();
        for (int c = T1pb; c < tpb; c += T1PB_MAX) {
            int n = (tpb - c) < T1PB_MAX ? (tpb - c) : T1PB_MAX;
            size_t cb = ((size_t)blk * tpb + c) * NPATCH;
            for (int i = tid; i < n * NPATCH; i += 256) sc[i] = counts[cb + i];
            __syncthreads();
            if (tid < NPATCH) {
                unsigned run = s_tot[tid];
                for (int tt = 0; tt < n; ++tt) {
                    unsigned v = sc[tt * NPATCH + tid];
                    sc[tt * NPATCH + tid] = run;
                    run += v;
                }
                s_tot[tid] = run;
            }
            __syncthreads();
            for (int i = tid; i < n * NPATCH; i += 256) counts[cb + i] = sc[i];
            __syncthreads();
        }
        float4 z = make_float4(0.f, 0.f, 0.f, 0.f);
        for (int p = 0; p < NPATCH; ++p) {
            unsigned total = s_tot[p];
            unsigned start = total < cap ? total : cap;
            size_t gb = ((size_t)blk * NPATCH + p) * cap;
            for (unsigned idx = start + tid; idx < cap; idx += 256) {
                ((float4*)out)[gb + idx] = z;
                out_mask[gb + idx] = 0.0f;
            }
        }
    }
    __threadfence();
    grid.sync();

    // D2: scatter suffix tiles (grid-stride, staged through LDS)
    for (int s = blk; s < B * nsuf; s += gridDim.x) {
        int b2 = s / nsuf;
        if (satflag[b2]) continue;  // block-uniform
        int t2 = b2 * tpb + T1pb + (s - b2 * nsuf);
        __syncthreads();
        if (tid < 64) wh[tid >> 4][tid & 15] = 0;
        if (tid == 0) s_flag = 0;
        __syncthreads();
        const size_t gbase = (size_t)t2 * TILE;
        for (int it = 0; it < ITERS; ++it) {
            int idx = w * CHUNK + it * 64 + lane;
            float4 e = ev[gbase + idx];
            s_ev[idx] = e;
            int p = patch_of(e.x, e.y);
            unsigned long long same = same_mask4(p);
            if ((same & lt) == 0ull) wh[w][p] += (unsigned)__popcll(same);
        }
        __syncthreads();
        if (tid < NPATCH) {
            unsigned v = counts[(size_t)t2 * NPATCH + tid];
            base_off[tid] = v;
            if (v < cap) s_flag = 1;  // benign race
        }
        __syncthreads();
        if (!s_flag) continue;
        if (tid < 64) {
            int ww = tid >> 4, p = tid & 15;
            unsigned v = base_off[p];
            for (int w2 = 0; w2 < ww; ++w2) v += wh[w2][p];
            cnt[ww][p] = v;
        }
        __syncthreads();
        for (int it = 0; it < ITERS; ++it) {
            float4 e = s_ev[w * CHUNK + it * 64 + lane];
            int px = ((int)e.x) >> PATCH_SHIFT;
            px = px < 0 ? 0 : (px > GRID_W - 1 ? GRID_W - 1 : px);
            int py = ((int)e.y) >> PATCH_SHIFT;
            py = py < 0 ? 0 : (py > GRID_H - 1 ? GRID_H - 1 : py);
            int p = (py << 2) | px;
            unsigned long long same = same_mask4(p);
            unsigned before = (unsigned)__popcll(same & lt);
            unsigned cb2 = cnt[w][p];
            unsigned rank = cb2 + before;
            if (rank < cap) {
                size_t o = ((size_t)b2 * NPATCH + p) * cap + rank;
                float4 v;
                v.x = e.x - (float)(px << PATCH_SHIFT);
                v.y = e.y - (float)(py << PATCH_SHIFT);
                v.z = e.z;
                v.w = e.w;
                ((float4*)out)[o] = v;
                out_mask[o] = 1.0f;
            }
            if (before == 0) cnt[w][p] = cb2 + (unsigned)__popcll(same);
        }
    }
}

extern "C" void kernel_launch(void* const* d_in, const int* in_sizes, int n_in,
                              void* d_out, int out_size, void* d_ws, size_t ws_size,
                              hipStream_t stream) {
    const float4* events = (const float4*)d_in[0];
    const int* p_cap = (const int*)d_in[1];

    const long long N = (long long)in_sizes[0] / 4;  // B*S
    int B = (int)(N / S_LEN);
    const long long T = N / TILE;
    int tpb = S_LEN / TILE;  // 512
    int T1pb = (tpb >= 32) ? (tpb * 5) / 32 : tpb;  // 80
    if (T1pb > T1PB_MAX) T1pb = T1PB_MAX;

    unsigned* counts = (unsigned*)d_ws;
    unsigned* satflag = counts + (size_t)T * NPATCH;
    unsigned* tot1 = satflag + B;
    float* outf = (float*)d_out;

    void* args[] = {(void*)&events, (void*)&counts, (void*)&satflag, (void*)&tot1,
                    (void*)&p_cap,  (void*)&outf,   (void*)&tpb,     (void*)&T1pb,
                    (void*)&B};
    hipLaunchCooperativeKernel((const void*)k_fused, dim3(B * T1pb), dim3(256), args, 0,
                               stream);
}

// Round 6
// 72.935 us; speedup vs baseline: 3.6488x; 3.6488x over previous
//
#include <hip/hip_runtime.h>
#include <cstddef>

// VectorizedPatchfier: capacity-limited stable counting sort into per-patch buffers.
// B=8, S=1<<20, C=4, grid 4x4 patches of 128x128 over a 512x512 canvas.
// Two-phase count: only the first 5/32 of each batch is histogrammed; if every
// group saturates (total >= cap) within that prefix (true for uniform inputs at
// ~21 sigma) the suffix is never read. The per-batch scan runs in the LAST tile
// block of each batch (threadFenceReduction pattern) -- no separate meta launch,
// no grid.sync (round-5 lesson: cooperative grid.sync costs ~100us/sync here).

#define GRID_W 4
#define GRID_H 4
#define NPATCH 16
#define PATCH_SHIFT 7   // 128
#define S_LEN (1 << 20)
#define T1PB_MAX 128

__device__ __forceinline__ int patch_of(float fx, float fy) {
    int px = ((int)fx) >> PATCH_SHIFT;
    int py = ((int)fy) >> PATCH_SHIFT;
    px = px < 0 ? 0 : (px > GRID_W - 1 ? GRID_W - 1 : px);
    py = py < 0 ? 0 : (py > GRID_H - 1 ? GRID_H - 1 : py);
    return (py << 2) | px;
}

// Per-wave: mask of lanes whose 4-bit patch id matches this lane's.
__device__ __forceinline__ unsigned long long same_mask4(int p) {
    unsigned long long same = ~0ull;
#pragma unroll
    for (int b = 0; b < 4; ++b) {
        unsigned long long bal = __ballot((p >> b) & 1);
        same &= ((p >> b) & 1) ? bal : ~bal;
    }
    return same;
}

// K1: histogram of phase-1 tiles; the last-finishing block of each batch also
// scans that batch's counts in LDS (and runs the general-case suffix fallback).
__global__ void k_histscan(const float4* __restrict__ ev, unsigned* __restrict__ counts,
                           unsigned* __restrict__ whist_g, unsigned* __restrict__ done,
                           unsigned* __restrict__ satflag, const int* __restrict__ p_cap,
                           float* __restrict__ out, int tile, int tpb, int T1pb, int B) {
    const int blk = blockIdx.x;
    const int b = blk / T1pb, tloc = blk - b * T1pb;
    const int t = b * tpb + tloc;
    const int tid = threadIdx.x, lane = tid & 63, w = tid >> 6;
    const unsigned cap = (unsigned)p_cap[0];
    __shared__ unsigned wh[4][NPATCH];
    __shared__ int s_last;
    if (tid < 64) wh[tid >> 4][tid & 15] = 0;
    __syncthreads();
    const int chunk = tile >> 2, iters = chunk >> 6;
    const size_t cbase = (size_t)t * tile + (size_t)w * chunk;
    const unsigned long long lt = (1ull << lane) - 1ull;
    for (int it = 0; it < iters; ++it) {
        float4 e = ev[cbase + (size_t)it * 64 + lane];
        int p = patch_of(e.x, e.y);
        unsigned long long same = same_mask4(p);
        if ((same & lt) == 0ull) wh[w][p] += (unsigned)__popcll(same);
    }
    __syncthreads();
    if (tid < 64) whist_g[(size_t)blk * 64 + tid] = wh[tid >> 4][tid & 15];
    if (tid < NPATCH)
        counts[(size_t)t * NPATCH + tid] =
            wh[0][tid] + wh[1][tid] + wh[2][tid] + wh[3][tid];

    // ---- last-block election for this batch ----
    __threadfence();  // release counts/whist stores device-wide
    if (tid == 0) {
        unsigned old = atomicAdd(&done[b], 1u);
        s_last = (old == (unsigned)(T1pb - 1));
    }
    __syncthreads();
    if (!s_last) return;
    __threadfence();  // acquire side

    // ---- meta (one block per batch): scan prefix counts, saturation check ----
    __shared__ unsigned sc[T1PB_MAX * NPATCH];
    __shared__ unsigned s_tot[NPATCH];
    __shared__ int s_ok;
    const size_t cb0 = (size_t)b * tpb * NPATCH;
    for (int i = tid; i < T1pb * NPATCH; i += 256)
        sc[i] = __hip_atomic_load(&counts[cb0 + i], __ATOMIC_RELAXED,
                                  __HIP_MEMORY_SCOPE_AGENT);
    if (tid == 0) s_ok = 1;
    __syncthreads();
    if (tid < NPATCH) {
        unsigned run = 0;
        for (int tt = 0; tt < T1pb; ++tt) {
            unsigned v = sc[tt * NPATCH + tid];
            sc[tt * NPATCH + tid] = run;
            run += v;
        }
        s_tot[tid] = run;
        if (run < cap) s_ok = 0;  // benign race: all writers store 0
    }
    __syncthreads();
    for (int i = tid; i < T1pb * NPATCH; i += 256) counts[cb0 + i] = sc[i];
    if (tid == 0) satflag[b] = (unsigned)s_ok;
    if (s_ok) return;

    // ---- fallback (general case): count+scan the suffix, zero unfilled tails ----
    __shared__ unsigned running[NPATCH];
    if (tid < NPATCH) running[tid] = s_tot[tid];
    for (int t2 = T1pb; t2 < tpb; ++t2) {
        if (tid < 64) wh[tid >> 4][tid & 15] = 0;
        __syncthreads();
        const size_t cb2 = ((size_t)(b * tpb + t2)) * tile + (size_t)w * chunk;
        for (int it = 0; it < iters; ++it) {
            float4 e = ev[cb2 + (size_t)it * 64 + lane];
            int p = patch_of(e.x, e.y);
            unsigned long long same = same_mask4(p);
            if ((same & lt) == 0ull) wh[w][p] += (unsigned)__popcll(same);
        }
        __syncthreads();
        if (tid < NPATCH) {
            counts[((size_t)(b * tpb + t2)) * NPATCH + tid] = running[tid];
            running[tid] += wh[0][tid] + wh[1][tid] + wh[2][tid] + wh[3][tid];
        }
        __syncthreads();
    }
    float* __restrict__ out_mask = out + (size_t)B * NPATCH * cap * 4;
    float4 z = make_float4(0.f, 0.f, 0.f, 0.f);
    for (int p = 0; p < NPATCH; ++p) {
        unsigned total = running[p];
        unsigned start = total < cap ? total : cap;
        size_t gb = ((size_t)b * NPATCH + p) * cap;
        for (unsigned idx = start + tid; idx < cap; idx += 256) {
            ((float4*)out)[gb + idx] = z;
            out_mask[gb + idx] = 0.0f;
        }
    }
}

// K2: one block per PREFIX tile (B*T1pb blocks). Scatters its tile using the
// saved per-wave hists. Suffix tiles only matter when a batch failed to
// saturate; handled by the grid-stride fallback loop (never triggered here).
__global__ void k_scatter(const float4* __restrict__ ev, const unsigned* __restrict__ offs,
                          const unsigned* __restrict__ whist_g,
                          const unsigned* __restrict__ satflag,
                          const int* __restrict__ p_cap, float* __restrict__ out,
                          int tile, int tpb, int T1pb, int B) {
    const int blk = blockIdx.x;
    const int b = blk / T1pb, tloc = blk - b * T1pb;
    const int t = b * tpb + tloc;
    const int tid = threadIdx.x, lane = tid & 63, w = tid >> 6;
    const unsigned cap = (unsigned)p_cap[0];
    __shared__ int s_any;
    __shared__ unsigned base_off[NPATCH];
    __shared__ unsigned cnt[4][NPATCH];
    __shared__ unsigned wh[4][NPATCH];
    const int chunk = tile >> 2, iters = chunk >> 6;
    const unsigned long long lt = (1ull << lane) - 1ull;
    float* __restrict__ out_mask = out + (size_t)B * NPATCH * cap * 4;

    if (tid == 0) s_any = 0;
    __syncthreads();
    if (tid < 16) {
        unsigned v = offs[(size_t)t * NPATCH + tid];
        base_off[tid] = v;
        if (v < cap) s_any = 1;  // benign race
    }
    __syncthreads();
    if (s_any) {
        if (tid < 64) {
            int ww = tid >> 4, p = tid & 15;
            unsigned s = base_off[p];
            const unsigned* whp = whist_g + (size_t)blk * 64;
            for (int w2 = 0; w2 < ww; ++w2) s += whp[w2 * 16 + p];
            cnt[ww][p] = s;
        }
        __syncthreads();
        const size_t cbase = (size_t)t * tile + (size_t)w * chunk;
        for (int it = 0; it < iters; ++it) {
            float4 e = ev[cbase + (size_t)it * 64 + lane];
            int px = ((int)e.x) >> PATCH_SHIFT;
            px = px < 0 ? 0 : (px > GRID_W - 1 ? GRID_W - 1 : px);
            int py = ((int)e.y) >> PATCH_SHIFT;
            py = py < 0 ? 0 : (py > GRID_H - 1 ? GRID_H - 1 : py);
            int p = (py << 2) | px;
            unsigned long long same = same_mask4(p);
            unsigned before = (unsigned)__popcll(same & lt);
            unsigned cb = cnt[w][p];
            unsigned rank = cb + before;
            if (rank < cap) {
                size_t o = ((size_t)b * NPATCH + p) * cap + rank;
                float4 v;
                v.x = e.x - (float)(px << PATCH_SHIFT);
                v.y = e.y - (float)(py << PATCH_SHIFT);
                v.z = e.z;
                v.w = e.w;
                ((float4*)out)[o] = v;
                out_mask[o] = 1.0f;
            }
            if (before == 0) cnt[w][p] = cb + (unsigned)__popcll(same);
        }
    }

    // ---- fallback: scatter suffix tiles of unsaturated batches (grid-stride) ----
    const int nsuf = tpb - T1pb;
    for (int s = blk; s < B * nsuf; s += gridDim.x) {
        int b2 = s / nsuf;
        if (satflag[b2]) continue;  // block-uniform
        int t2 = b2 * tpb + T1pb + (s - b2 * nsuf);
        __syncthreads();
        if (tid < 64) wh[tid >> 4][tid & 15] = 0;
        if (tid == 0) s_any = 0;
        __syncthreads();
        const size_t cb2 = (size_t)t2 * tile + (size_t)w * chunk;
        for (int it = 0; it < iters; ++it) {
            float4 e = ev[cb2 + (size_t)it * 64 + lane];
            int p = patch_of(e.x, e.y);
            unsigned long long same = same_mask4(p);
            if ((same & lt) == 0ull) wh[w][p] += (unsigned)__popcll(same);
        }
        __syncthreads();
        if (tid < 16) {
            unsigned v = offs[(size_t)t2 * NPATCH + tid];
            base_off[tid] = v;
            if (v < cap) s_any = 1;  // benign race
        }
        __syncthreads();
        if (!s_any) continue;
        if (tid < 64) {
            int ww = tid >> 4, p = tid & 15;
            unsigned v = base_off[p];
            for (int w2 = 0; w2 < ww; ++w2) v += wh[w2][p];
            cnt[ww][p] = v;
        }
        __syncthreads();
        for (int it = 0; it < iters; ++it) {
            float4 e = ev[cb2 + (size_t)it * 64 + lane];
            int px = ((int)e.x) >> PATCH_SHIFT;
            px = px < 0 ? 0 : (px > GRID_W - 1 ? GRID_W - 1 : px);
            int py = ((int)e.y) >> PATCH_SHIFT;
            py = py < 0 ? 0 : (py > GRID_H - 1 ? GRID_H - 1 : py);
            int p = (py << 2) | px;
            unsigned long long same = same_mask4(p);
            unsigned before = (unsigned)__popcll(same & lt);
            unsigned cb = cnt[w][p];
            unsigned rank = cb + before;
            if (rank < cap) {
                size_t o = ((size_t)b2 * NPATCH + p) * cap + rank;
                float4 v;
                v.x = e.x - (float)(px << PATCH_SHIFT);
                v.y = e.y - (float)(py << PATCH_SHIFT);
                v.z = e.z;
                v.w = e.w;
                ((float4*)out)[o] = v;
                out_mask[o] = 1.0f;
            }
            if (before == 0) cnt[w][p] = cb + (unsigned)__popcll(same);
        }
    }
}

extern "C" void kernel_launch(void* const* d_in, const int* in_sizes, int n_in,
                              void* d_out, int out_size, void* d_ws, size_t ws_size,
                              hipStream_t stream) {
    const float* events = (const float*)d_in[0];
    const int* p_cap = (const int*)d_in[1];

    const int C = 4;
    const long long N = (long long)in_sizes[0] / C;  // B*S
    const int B = (int)(N / S_LEN);

    int tile = 2048, tpb, T1pb;
    for (;;) {
        long long T = N / tile;
        tpb = (int)(S_LEN / tile);
        T1pb = tpb;
        if (tpb >= 32) T1pb = (tpb * 5) / 32;   // 80 tiles at tile=2048
        if (T1pb > T1PB_MAX) T1pb = T1PB_MAX;
        size_t need = ((size_t)T * NPATCH + (size_t)B * T1pb * 64 + 2 * (size_t)B) *
                      sizeof(unsigned);
        if (need <= ws_size || tile >= S_LEN) break;
        tile <<= 1;
    }
    const int T = (int)(N / tile);

    unsigned* counts = (unsigned*)d_ws;
    unsigned* whist_g = counts + (size_t)T * NPATCH;
    unsigned* satflag = whist_g + (size_t)B * T1pb * 64;
    unsigned* done = satflag + B;

    hipMemsetAsync(done, 0, (size_t)B * sizeof(unsigned), stream);
    k_histscan<<<B * T1pb, 256, 0, stream>>>((const float4*)events, counts, whist_g,
                                             done, satflag, p_cap, (float*)d_out,
                                             tile, tpb, T1pb, B);
    k_scatter<<<B * T1pb, 256, 0, stream>>>((const float4*)events, counts, whist_g,
                                            satflag, p_cap, (float*)d_out,
                                            tile, tpb, T1pb, B);
}

// Round 7
// 31.608 us; speedup vs baseline: 8.4197x; 2.3075x over previous
//
#include <hip/hip_runtime.h>
#include <cstddef>

// VectorizedPatchfier: capacity-limited stable counting sort into per-patch buffers.
// B=8, S=1<<20, C=4, grid 4x4 patches of 128x128 over a 512x512 canvas.
//
// Single-pass decoupled-lookback counting sort over the first 5/32 of each batch
// (prefix saturates every group at ~21 sigma for uniform input). One kernel:
// load tile->LDS, hist, publish count (relaxed agent atomics: payload-only
// coherence, NO __threadfence -- r6 lesson: per-block device fences cost ~70us),
// lookback within batch, scatter from LDS. Ticket-ordered tile assignment makes
// lookback deadlock-free (dependencies point at already-started blocks).
// Generality: last prefix block of an unsaturated batch serially handles the
// suffix + tail zeroing (never triggered for the bench input).

#define GRID_W 4
#define GRID_H 4
#define NPATCH 16
#define PATCH_SHIFT 7   // 128
#define S_LEN (1 << 20)
#define TILE 2048
#define CHUNK (TILE / 4)    // events per wave
#define ITERS (CHUNK / 64)  // inner iters per wave
#define AGGF (1u << 30)
#define PREF (1u << 31)
#define VALM (AGGF - 1u)

__device__ __forceinline__ int patch_of(float fx, float fy) {
    int px = ((int)fx) >> PATCH_SHIFT;
    int py = ((int)fy) >> PATCH_SHIFT;
    px = px < 0 ? 0 : (px > GRID_W - 1 ? GRID_W - 1 : px);
    py = py < 0 ? 0 : (py > GRID_H - 1 ? GRID_H - 1 : py);
    return (py << 2) | px;
}

// Per-wave: mask of lanes whose 4-bit patch id matches this lane's.
__device__ __forceinline__ unsigned long long same_mask4(int p) {
    unsigned long long same = ~0ull;
#pragma unroll
    for (int b = 0; b < 4; ++b) {
        unsigned long long bal = __ballot((p >> b) & 1);
        same &= ((p >> b) & 1) ? bal : ~bal;
    }
    return same;
}

__device__ __forceinline__ unsigned st_ld(const unsigned* a) {
    return __hip_atomic_load(a, __ATOMIC_RELAXED, __HIP_MEMORY_SCOPE_AGENT);
}
__device__ __forceinline__ void st_st(unsigned* a, unsigned v) {
    __hip_atomic_store(a, v, __ATOMIC_RELAXED, __HIP_MEMORY_SCOPE_AGENT);
}

__global__ __launch_bounds__(256, 3) void k_onepass(
    const float4* __restrict__ ev, unsigned* __restrict__ ticket,
    unsigned* __restrict__ state, const int* __restrict__ p_cap,
    float* __restrict__ out, int tpb, int T1pb, int B) {
    const int tid = threadIdx.x, lane = tid & 63, w = tid >> 6;
    const unsigned cap = (unsigned)p_cap[0];
    const unsigned long long lt = (1ull << lane) - 1ull;
    __shared__ float4 s_ev[TILE];  // 32 KB: this block's tile
    __shared__ unsigned wh[4][NPATCH];
    __shared__ unsigned cnt[4][NPATCH];
    __shared__ unsigned base_off[NPATCH];
    __shared__ unsigned s_run[NPATCH];
    __shared__ int s_tk, s_any, s_ok;
    float* __restrict__ out_mask = out + (size_t)B * NPATCH * cap * 4;

    if (tid == 0) {
        s_tk = (int)atomicAdd(ticket, 1u);  // execution-ordered tile id
        s_any = 0;
    }
    if (tid < 64) wh[tid >> 4][tid & 15] = 0;
    __syncthreads();
    const int k = s_tk;
    const int b = k / T1pb, tloc = k - b * T1pb;
    const int t = b * tpb + tloc;

    // ---- Phase A: load own tile to LDS + per-wave histogram ----
    const size_t gbase = (size_t)t * TILE;
    for (int it = 0; it < ITERS; ++it) {
        int idx = w * CHUNK + it * 64 + lane;
        float4 e = ev[gbase + idx];
        s_ev[idx] = e;
        int p = patch_of(e.x, e.y);
        unsigned long long same = same_mask4(p);
        if ((same & lt) == 0ull) wh[w][p] += (unsigned)__popcll(same);
    }
    __syncthreads();

    // ---- Phase B: publish aggregate, decoupled lookback within batch ----
    if (tid < NPATCH) {
        const unsigned tot =
            wh[0][tid] + wh[1][tid] + wh[2][tid] + wh[3][tid];
        st_st(&state[(size_t)k * NPATCH + tid], tot | AGGF);
        unsigned sum = 0;
        int j = tloc - 1;
        const size_t brow = (size_t)b * T1pb;
        while (j >= 0) {
            const int navail = (j + 1 < 4) ? (j + 1) : 4;
            unsigned v[4];
#pragma unroll
            for (int q = 0; q < 4; ++q)
                v[q] = (q < navail) ? st_ld(&state[(brow + (j - q)) * NPATCH + tid]) : 0u;
            bool done = false, blocked = false;
            int adv = 0;
#pragma unroll
            for (int q = 0; q < 4; ++q) {
                if (q >= navail || done || blocked) continue;
                unsigned x = v[q];
                if (x & PREF) { sum += x & VALM; done = true; }
                else if (x & AGGF) { sum += x & VALM; ++adv; }
                else blocked = true;
            }
            if (done) break;
            j -= adv;
            if (adv == 0) __builtin_amdgcn_s_sleep(1);
        }
        base_off[tid] = sum;
        if (sum < cap) s_any = 1;  // benign race: all writers store 1
        st_st(&state[(size_t)k * NPATCH + tid], (sum + tot) | PREF | AGGF);
        s_run[tid] = sum + tot;  // inclusive prefix (last block: batch totals)
    }
    __syncthreads();

    // ---- Phase C: scatter own tile from LDS ----
    if (s_any) {
        if (tid < 64) {
            int ww = tid >> 4, p = tid & 15;
            unsigned s = base_off[p];
            for (int w2 = 0; w2 < ww; ++w2) s += wh[w2][p];
            cnt[ww][p] = s;
        }
        __syncthreads();
        for (int it = 0; it < ITERS; ++it) {
            float4 e = s_ev[w * CHUNK + it * 64 + lane];
            int px = ((int)e.x) >> PATCH_SHIFT;
            px = px < 0 ? 0 : (px > GRID_W - 1 ? GRID_W - 1 : px);
            int py = ((int)e.y) >> PATCH_SHIFT;
            py = py < 0 ? 0 : (py > GRID_H - 1 ? GRID_H - 1 : py);
            int p = (py << 2) | px;
            unsigned long long same = same_mask4(p);
            unsigned before = (unsigned)__popcll(same & lt);
            unsigned cb = cnt[w][p];
            unsigned rank = cb + before;
            if (rank < cap) {
                size_t o = ((size_t)b * NPATCH + p) * cap + rank;
                float4 v;
                v.x = e.x - (float)(px << PATCH_SHIFT);
                v.y = e.y - (float)(py << PATCH_SHIFT);
                v.z = e.z;
                v.w = e.w;
                ((float4*)out)[o] = v;
                out_mask[o] = 1.0f;
            }
            if (before == 0) cnt[w][p] = cb + (unsigned)__popcll(same);
        }
    }

    // ---- Phase D (general-case fallback; never triggered for uniform input):
    // last prefix block of an unsaturated batch handles the whole suffix. ----
    if (tloc != T1pb - 1) return;
    if (tid == 0) s_ok = 1;
    __syncthreads();
    if (tid < NPATCH && s_run[tid] < cap) s_ok = 0;  // benign race
    __syncthreads();
    if (s_ok) return;

    for (int t2 = T1pb; t2 < tpb; ++t2) {
        __syncthreads();
        if (tid < 64) wh[tid >> 4][tid & 15] = 0;
        __syncthreads();
        const size_t g2 = ((size_t)(b * tpb + t2)) * TILE;
        for (int it = 0; it < ITERS; ++it) {
            int idx = w * CHUNK + it * 64 + lane;
            float4 e = ev[g2 + idx];
            s_ev[idx] = e;
            int p = patch_of(e.x, e.y);
            unsigned long long same = same_mask4(p);
            if ((same & lt) == 0ull) wh[w][p] += (unsigned)__popcll(same);
        }
        __syncthreads();
        if (tid < 64) {
            int ww = tid >> 4, p = tid & 15;
            unsigned s = s_run[p];
            for (int w2 = 0; w2 < ww; ++w2) s += wh[w2][p];
            cnt[ww][p] = s;
        }
        __syncthreads();
        for (int it = 0; it < ITERS; ++it) {
            float4 e = s_ev[w * CHUNK + it * 64 + lane];
            int px = ((int)e.x) >> PATCH_SHIFT;
            px = px < 0 ? 0 : (px > GRID_W - 1 ? GRID_W - 1 : px);
            int py = ((int)e.y) >> PATCH_SHIFT;
            py = py < 0 ? 0 : (py > GRID_H - 1 ? GRID_H - 1 : py);
            int p = (py << 2) | px;
            unsigned long long same = same_mask4(p);
            unsigned before = (unsigned)__popcll(same & lt);
            unsigned cb = cnt[w][p];
            unsigned rank = cb + before;
            if (rank < cap) {
                size_t o = ((size_t)b * NPATCH + p) * cap + rank;
                float4 v;
                v.x = e.x - (float)(px << PATCH_SHIFT);
                v.y = e.y - (float)(py << PATCH_SHIFT);
                v.z = e.z;
                v.w = e.w;
                ((float4*)out)[o] = v;
                out_mask[o] = 1.0f;
            }
            if (before == 0) cnt[w][p] = cb + (unsigned)__popcll(same);
        }
        __syncthreads();
        if (tid < NPATCH)
            s_run[tid] += wh[0][tid] + wh[1][tid] + wh[2][tid] + wh[3][tid];
    }
    __syncthreads();
    float4 z = make_float4(0.f, 0.f, 0.f, 0.f);
    for (int p = 0; p < NPATCH; ++p) {
        unsigned total = s_run[p];
        unsigned start = total < cap ? total : cap;
        size_t gb = ((size_t)b * NPATCH + p) * cap;
        for (unsigned idx = start + tid; idx < cap; idx += 256) {
            ((float4*)out)[gb + idx] = z;
            out_mask[gb + idx] = 0.0f;
        }
    }
}

extern "C" void kernel_launch(void* const* d_in, const int* in_sizes, int n_in,
                              void* d_out, int out_size, void* d_ws, size_t ws_size,
                              hipStream_t stream) {
    const float* events = (const float*)d_in[0];
    const int* p_cap = (const int*)d_in[1];

    const int C = 4;
    const long long N = (long long)in_sizes[0] / C;  // B*S
    const int B = (int)(N / S_LEN);
    const int tpb = S_LEN / TILE;  // 512
    int T1pb = (tpb >= 32) ? (tpb * 5) / 32 : tpb;  // 80
    const int NT = B * T1pb;  // 640

    unsigned* ticket = (unsigned*)d_ws;
    unsigned* state = ticket + 16;  // 64-B aligned header

    hipMemsetAsync(d_ws, 0, 64 + (size_t)NT * NPATCH * sizeof(unsigned), stream);
    k_onepass<<<NT, 256, 0, stream>>>((const float4*)events, ticket, state, p_cap,
                                      (float*)d_out, tpb, T1pb, B);
}